// Round 1
// baseline (131.943 us; speedup 1.0000x reference)
//
#include <hip/hip_runtime.h>
#include <hip/hip_bf16.h>

// Problem constants (BatchSparseDenseMatmul): B=128, R=8192, C=16384, NNZ=524288
#define BN 128
#define RN 8192
#define CN 16384

// ---------------- CSR build ----------------

__global__ void hist_kernel(const int* __restrict__ rows, int* __restrict__ counts, int nnz) {
    int i = blockIdx.x * blockDim.x + threadIdx.x;
    if (i < nnz) atomicAdd(&counts[rows[i]], 1);
}

// Single-block exclusive scan over R counts -> row_start[R+1]
__global__ void scan_kernel(const int* __restrict__ counts, int* __restrict__ row_start, int R) {
    __shared__ int smem[256];
    __shared__ int running;
    if (threadIdx.x == 0) running = 0;
    __syncthreads();
    for (int base = 0; base < R; base += 256) {
        int v = counts[base + threadIdx.x];
        smem[threadIdx.x] = v;
        __syncthreads();
        // Hillis-Steele inclusive scan
        for (int off = 1; off < 256; off <<= 1) {
            int add = (threadIdx.x >= off) ? smem[threadIdx.x - off] : 0;
            __syncthreads();
            smem[threadIdx.x] += add;
            __syncthreads();
        }
        int incl = smem[threadIdx.x];
        int excl = incl - v;
        row_start[base + threadIdx.x] = running + excl;
        __syncthreads();                 // everyone reads `running` before update
        if (threadIdx.x == 255) running += incl;
        __syncthreads();
    }
    if (threadIdx.x == 0) row_start[R] = running;
}

__global__ void copy_int_kernel(const int* __restrict__ src, int* __restrict__ dst, int n) {
    int i = blockIdx.x * blockDim.x + threadIdx.x;
    if (i < n) dst[i] = src[i];
}

__global__ void scatter_kernel(const int* __restrict__ rows, const int* __restrict__ cols,
                               const float* __restrict__ vals,
                               int* __restrict__ cursor,
                               int* __restrict__ scol, float* __restrict__ sval, int nnz) {
    int i = blockIdx.x * blockDim.x + threadIdx.x;
    if (i < nnz) {
        int r = rows[i];
        int p = atomicAdd(&cursor[r], 1);
        scol[p] = cols[i];
        sval[p] = vals[i];
    }
}

// ---------------- transposes ----------------

// x [B][C] -> xT [C][B]   (256 threads = 32x8)
__global__ void transpose_x_kernel(const float* __restrict__ x, float* __restrict__ xT) {
    __shared__ float tile[32][33];
    int cBase = blockIdx.x * 32;
    int bBase = blockIdx.y * 32;
    int tx = threadIdx.x & 31;
    int ty = threadIdx.x >> 5;   // 0..7
    #pragma unroll
    for (int i = ty; i < 32; i += 8)
        tile[i][tx] = x[(bBase + i) * CN + cBase + tx];
    __syncthreads();
    #pragma unroll
    for (int i = ty; i < 32; i += 8)
        xT[(cBase + i) * BN + bBase + tx] = tile[tx][i];
}

// outT [R][B] -> out [B][R]
__global__ void transpose_out_kernel(const float* __restrict__ outT, float* __restrict__ out) {
    __shared__ float tile[32][33];
    int rBase = blockIdx.x * 32;
    int bBase = blockIdx.y * 32;
    int tx = threadIdx.x & 31;
    int ty = threadIdx.x >> 5;
    #pragma unroll
    for (int i = ty; i < 32; i += 8)
        tile[i][tx] = outT[(rBase + i) * BN + bBase + tx];
    __syncthreads();
    #pragma unroll
    for (int i = ty; i < 32; i += 8)
        out[(bBase + i) * RN + rBase + tx] = tile[tx][i];
}

// ---------------- SpMM ----------------

// One block (128 threads = batch lanes) per row.
__global__ void __launch_bounds__(128) spmm_kernel(const float* __restrict__ xT,
                            const int* __restrict__ row_start,
                            const int* __restrict__ scol,
                            const float* __restrict__ sval,
                            float* __restrict__ outT) {
    int r = blockIdx.x;
    int b = threadIdx.x;        // 0..127
    int start = row_start[r];
    int end   = row_start[r + 1];

    __shared__ int   s_col[128];
    __shared__ float s_val[128];

    float acc = 0.f;
    for (int base = start; base < end; base += 128) {
        int n = min(128, end - base);
        if (threadIdx.x < n) {
            s_col[threadIdx.x] = scol[base + threadIdx.x];
            s_val[threadIdx.x] = sval[base + threadIdx.x];
        }
        __syncthreads();
        for (int j = 0; j < n; ++j)
            acc += s_val[j] * xT[s_col[j] * BN + b];
        __syncthreads();
    }
    outT[r * BN + b] = acc;
}

// ---------------- launch ----------------

extern "C" void kernel_launch(void* const* d_in, const int* in_sizes, int n_in,
                              void* d_out, int out_size, void* d_ws, size_t ws_size,
                              hipStream_t stream) {
    const float* x      = (const float*)d_in[0];   // [B*C]
    const float* vals   = (const float*)d_in[1];   // [NNZ]
    const int*   rows   = (const int*)d_in[2];     // [NNZ]
    const int*   cols   = (const int*)d_in[3];     // [NNZ]
    float*       out    = (float*)d_out;           // [B*R]
    const int nnz = in_sizes[1];

    // workspace layout
    char* ws = (char*)d_ws;
    float* xT        = (float*)(ws);                              // C*B floats = 8 MB
    float* outT      = (float*)(ws + (size_t)CN * BN * 4);        // R*B floats = 4 MB
    float* sval      = (float*)(ws + (size_t)(CN * BN + RN * BN) * 4);          // NNZ
    int*   scol      = (int*)  (ws + (size_t)(CN * BN + RN * BN + nnz) * 4);    // NNZ
    int*   row_start = (int*)  (ws + (size_t)(CN * BN + RN * BN + 2 * nnz) * 4);// R+1
    int*   counts    = row_start + (RN + 1);                                    // R
    int*   cursor    = counts + RN;                                             // R

    // 1. zero histogram
    hipMemsetAsync(counts, 0, RN * sizeof(int), stream);

    // 2. histogram of rows
    hist_kernel<<<(nnz + 255) / 256, 256, 0, stream>>>(rows, counts, nnz);

    // 3. exclusive scan -> row_start
    scan_kernel<<<1, 256, 0, stream>>>(counts, row_start, RN);

    // 4. cursor = row_start[0..R)
    copy_int_kernel<<<(RN + 255) / 256, 256, 0, stream>>>(row_start, cursor, RN);

    // 5. scatter into CSR order
    scatter_kernel<<<(nnz + 255) / 256, 256, 0, stream>>>(rows, cols, vals, cursor, scol, sval, nnz);

    // 6. transpose x -> xT [C][B]
    transpose_x_kernel<<<dim3(CN / 32, BN / 32), 256, 0, stream>>>(x, xT);

    // 7. SpMM: outT[r][b]
    spmm_kernel<<<RN, 128, 0, stream>>>(xT, row_start, scol, sval, outT);

    // 8. transpose outT -> out [B][R]
    transpose_out_kernel<<<dim3(RN / 32, BN / 32), 256, 0, stream>>>(outT, out);
}

// Round 2
// 93.120 us; speedup vs baseline: 1.4169x; 1.4169x over previous
//
#include <hip/hip_runtime.h>
#include <hip/hip_bf16.h>

// Problem constants (BatchSparseDenseMatmul): B=128, R=8192, C=16384, NNZ=524288
#define BN 128
#define RN 8192
#define CN 16384

// ---------------- zero counts ----------------
__global__ void zero_kernel(int* __restrict__ counts) {
    int i = blockIdx.x * blockDim.x + threadIdx.x;
    if (i < RN) counts[i] = 0;
}

// ---------------- fused transpose_x + histogram ----------------
// blocks [0, 2048): transpose x [B][C] -> xT [C][B]  (32x32 tiles, 256 thr)
// blocks [2048, 4096): histogram of rows (256 thr each -> exactly NNZ threads)
__global__ void __launch_bounds__(256) txpose_hist_kernel(
        const float* __restrict__ x, float* __restrict__ xT,
        const int* __restrict__ rows, int* __restrict__ counts, int nnz) {
    if (blockIdx.x < 2048) {
        __shared__ float tile[32][33];
        int bx = blockIdx.x;
        int cBase = (bx & 511) * 32;   // C/32 = 512 tiles along C
        int bBase = (bx >> 9) * 32;    // B/32 = 4 tiles along B
        int tx = threadIdx.x & 31;
        int ty = threadIdx.x >> 5;     // 0..7
        #pragma unroll
        for (int i = ty; i < 32; i += 8)
            tile[i][tx] = x[(bBase + i) * CN + cBase + tx];
        __syncthreads();
        #pragma unroll
        for (int i = ty; i < 32; i += 8)
            xT[(cBase + i) * BN + bBase + tx] = tile[tx][i];
    } else {
        int i = (blockIdx.x - 2048) * 256 + threadIdx.x;
        if (i < nnz) atomicAdd(&counts[rows[i]], 1);
    }
}

// ---------------- scan: one 1024-thread block, 8 elems/thread ----------------
__global__ void __launch_bounds__(1024) scan_kernel(const int* __restrict__ counts,
                                                    int* __restrict__ row_start,
                                                    int* __restrict__ cursor) {
    __shared__ int partial[1024];
    int tid = threadIdx.x;
    int base = tid * 8;
    int v[8];
    int sum = 0;
    #pragma unroll
    for (int i = 0; i < 8; ++i) { v[i] = counts[base + i]; sum += v[i]; }
    partial[tid] = sum;
    __syncthreads();
    // Hillis-Steele over 1024 partials (10 steps, 20 barriers)
    for (int off = 1; off < 1024; off <<= 1) {
        int add = (tid >= off) ? partial[tid - off] : 0;
        __syncthreads();
        partial[tid] += add;
        __syncthreads();
    }
    int run = partial[tid] - sum;   // exclusive prefix of this thread's chunk
    #pragma unroll
    for (int i = 0; i < 8; ++i) {
        row_start[base + i] = run;
        cursor[base + i]    = run;
        run += v[i];
    }
    if (tid == 1023) row_start[RN] = run;
}

// ---------------- scatter into CSR order (packed col+val, one 8B write) ----------------
__global__ void scatter_kernel(const int* __restrict__ rows, const int* __restrict__ cols,
                               const float* __restrict__ vals,
                               int* __restrict__ cursor,
                               int2* __restrict__ pk, int nnz) {
    int i = blockIdx.x * blockDim.x + threadIdx.x;
    if (i < nnz) {
        int r = rows[i];
        int p = atomicAdd(&cursor[r], 1);
        pk[p] = make_int2(cols[i], __float_as_int(vals[i]));
    }
}

// ---------------- SpMM: one 64-thread block per row, float2 per lane ----------------
__global__ void __launch_bounds__(64) spmm_kernel(const float* __restrict__ xT,
                            const int* __restrict__ row_start,
                            const int2* __restrict__ pk,
                            float* __restrict__ outT) {
    int r = blockIdx.x;
    int t = threadIdx.x;        // 0..63, owns batch elems 2t, 2t+1
    int start = row_start[r];
    int end   = row_start[r + 1];

    __shared__ int2 s_pk[64];

    float2 acc = make_float2(0.f, 0.f);
    for (int base = start; base < end; base += 64) {
        int n = min(64, end - base);
        if (t < n) s_pk[t] = pk[base + t];
        __syncthreads();
        #pragma unroll 4
        for (int j = 0; j < n; ++j) {
            int2 e = s_pk[j];
            float v = __int_as_float(e.y);
            float2 xv = *reinterpret_cast<const float2*>(&xT[e.x * BN + 2 * t]);
            acc.x += v * xv.x;
            acc.y += v * xv.y;
        }
        __syncthreads();
    }
    *reinterpret_cast<float2*>(&outT[r * BN + 2 * t]) = acc;
}

// ---------------- transpose outT [R][B] -> out [B][R] ----------------
__global__ void __launch_bounds__(256) transpose_out_kernel(const float* __restrict__ outT,
                                                            float* __restrict__ out) {
    __shared__ float tile[32][33];
    int rBase = blockIdx.x * 32;
    int bBase = blockIdx.y * 32;
    int tx = threadIdx.x & 31;
    int ty = threadIdx.x >> 5;
    #pragma unroll
    for (int i = ty; i < 32; i += 8)
        tile[i][tx] = outT[(rBase + i) * BN + bBase + tx];
    __syncthreads();
    #pragma unroll
    for (int i = ty; i < 32; i += 8)
        out[(bBase + i) * RN + rBase + tx] = tile[tx][i];
}

// ---------------- launch ----------------
extern "C" void kernel_launch(void* const* d_in, const int* in_sizes, int n_in,
                              void* d_out, int out_size, void* d_ws, size_t ws_size,
                              hipStream_t stream) {
    const float* x      = (const float*)d_in[0];   // [B*C]
    const float* vals   = (const float*)d_in[1];   // [NNZ]
    const int*   rows   = (const int*)d_in[2];     // [NNZ]
    const int*   cols   = (const int*)d_in[3];     // [NNZ]
    float*       out    = (float*)d_out;           // [B*R]
    const int nnz = in_sizes[1];

    // workspace layout (bytes)
    char* ws = (char*)d_ws;
    float* xT        = (float*)(ws);                                   // C*B   = 8 MB
    float* outT      = (float*)(ws + (size_t)CN * BN * 4);             // R*B   = 4 MB
    int2*  pk        = (int2*) (ws + (size_t)(CN * BN + RN * BN) * 4); // NNZ*8 = 4 MB
    int*   row_start = (int*)  (ws + (size_t)(CN * BN + RN * BN + 2 * nnz) * 4); // R+1
    int*   counts    = row_start + (RN + 1);
    int*   cursor    = counts + RN;

    // 1. zero histogram
    zero_kernel<<<RN / 256, 256, 0, stream>>>(counts);

    // 2. fused transpose_x + histogram
    txpose_hist_kernel<<<2048 + (nnz + 255) / 256, 256, 0, stream>>>(x, xT, rows, counts, nnz);

    // 3. exclusive scan -> row_start, cursor
    scan_kernel<<<1, 1024, 0, stream>>>(counts, row_start, cursor);

    // 4. scatter into CSR order (packed)
    scatter_kernel<<<(nnz + 255) / 256, 256, 0, stream>>>(rows, cols, vals, cursor, pk, nnz);

    // 5. SpMM: outT[r][b]
    spmm_kernel<<<RN, 64, 0, stream>>>(xT, row_start, pk, outT);

    // 6. transpose outT -> out [B][R]
    transpose_out_kernel<<<dim3(RN / 32, BN / 32), 256, 0, stream>>>(outT, out);
}